// Round 3
// baseline (52283.594 us; speedup 1.0000x reference)
//
#include <hip/hip_runtime.h>

// LSTM_15556371546645 — MI355X (gfx950), round 3
// Recurrence redesign: gates^T MFMA orientation (m=gate-row, n=batch) with a
// row permutation making each lane's f32x4 acc = (i,f,g,o) of one (j,b).
// W_hh entirely in VGPR fragments (128/lane), NO LDS in lstm_rec.
// h exchange: hx[b][256 j] bf16 via u64 relaxed agent atomics; 4-thread flag poll.
// xg layout [time*64+b][1024 row'] so gate bias init is one u64/acc.

typedef unsigned short u16;
typedef unsigned long long u64;
typedef __attribute__((ext_vector_type(8))) short short8;   // 8 x bf16 (4 VGPRs)
typedef __attribute__((ext_vector_type(4))) float f32x4;    // MFMA acc

#define SEQ  2048
#define CS   256            // chunk steps
#define NCH  (SEQ / CS)     // 8 chunks
#define CN   (CS * 64)      // rows per chunk = 16384

// ---------------- numeric helpers ----------------
__device__ __forceinline__ u16 f2bf(float f) {
  unsigned u = __float_as_uint(f);
  unsigned r = u + 0x7fffu + ((u >> 16) & 1u);   // RTNE
  return (u16)(r >> 16);
}
__device__ __forceinline__ float bf2f(u16 h) {
  return __uint_as_float(((unsigned)h) << 16);
}
__device__ __forceinline__ float sigf(float x) {
  return __builtin_amdgcn_rcpf(1.f + __expf(-x));
}
__device__ __forceinline__ float tanhf_fast(float x) {
  return 1.f - 2.f * __builtin_amdgcn_rcpf(1.f + __expf(2.f * x));
}

// Row permutation: row' = q*256 + T*16 + u  (T=0..15, u=0..15)
//   gate g = u&3 ;  j = (T>>2)*16 + (u>>2)*4 + (T&3) ;  r_orig = g*256 + q*64 + j
__device__ __forceinline__ int rowp_to_orig(int rowp) {
  int q = rowp >> 8, T = (rowp >> 4) & 15, u = rowp & 15;
  int g = u & 3;
  int j = ((T >> 2) << 4) + ((u >> 2) << 2) + (T & 3);
  return g * 256 + q * 64 + j;
}

// ---------------- prep: convert + permute + pack ----------------
#define S1 16384     // enc_w -> bf16
#define S2 16384     // dec_w -> bf16
#define S3 524288    // w_ih rows permuted to row' order, bf16 [l][row'][k]
#define S4 2048      // bias2[l][row'] = b_ih + b_hh at r_orig(row')
#define S5 524288    // w_hh A-fragment pack [l][q][w][t][kc][lane][8]
#define S6 16        // flags zero
#define PREP_TOTAL (S1 + S2 + S3 + S4 + S5 + S6)

__global__ void prep_kernel(const float* __restrict__ enc_w,
                            const float* __restrict__ w_ih, const float* __restrict__ w_hh,
                            const float* __restrict__ b_ih, const float* __restrict__ b_hh,
                            const float* __restrict__ dec_w,
                            u16* __restrict__ WENC, u16* __restrict__ WDEC,
                            u16* __restrict__ WIH, float* __restrict__ BIAS2,
                            u16* __restrict__ WHH, int* __restrict__ FLAGS)
{
  size_t idx = (size_t)blockIdx.x * 256 + threadIdx.x;
  if (idx < S1) { WENC[idx] = f2bf(enc_w[idx]); return; }
  idx -= S1;
  if (idx < S2) { WDEC[idx] = f2bf(dec_w[idx]); return; }
  idx -= S2;
  if (idx < S3) {   // [l][row'][k]
    int l = (int)(idx >> 18);
    int rem = (int)(idx & 262143);
    int rowp = rem >> 8, k = rem & 255;
    WIH[idx] = f2bf(w_ih[(size_t)l * 262144 + (size_t)rowp_to_orig(rowp) * 256 + k]);
    return;
  }
  idx -= S3;
  if (idx < S4) {   // bias2[l][row']
    int l = (int)(idx >> 10);
    int rowp = (int)(idx & 1023);
    int r = rowp_to_orig(rowp);
    BIAS2[idx] = b_ih[l * 1024 + r] + b_hh[l * 1024 + r];
    return;
  }
  idx -= S4;
  if (idx < S5) {   // W_hh A-frag pack: flat = ((((l*4+q)*4+w)*4+t)*8+kc)*512 + lane*8 + e
    int l = (int)(idx >> 18);
    int rem = (int)(idx & 262143);
    int e = rem & 7;
    int lane = (rem >> 3) & 63;
    int kc = (rem >> 9) & 7;
    int t = (rem >> 12) & 3;
    int wv = (rem >> 14) & 3;
    int q = (rem >> 16) & 3;
    int u = lane & 15, qd = lane >> 4;
    int g = u & 3;
    int j = wv * 16 + ((u >> 2) << 2) + t;
    int r = g * 256 + q * 64 + j;
    int k = kc * 32 + qd * 8 + e;
    WHH[idx] = f2bf(w_hh[(size_t)l * 262144 + (size_t)r * 256 + k]);
    return;
  }
  idx -= S5;
  if (idx < S6) FLAGS[idx] = 0;
}

// ---------------- generic bf16 GEMM:  C(MxN) = A(MxK) * B(NxK)^T + bias ----------------
// KTILES = K/64. OUTBF: 1 bf16 out, 0 fp32 out. BMODE: 1 bias[n], 2 bias[m].
// AF32: A is fp32, converted to bf16 during LDS staging.
template<int KTILES, int OUTBF, int BMODE, int AF32>
__global__ __launch_bounds__(256, 1) void gemm_bt(
    const void* __restrict__ Av, const u16* __restrict__ B, void* __restrict__ Cv,
    const float* __restrict__ bias, size_t ldc)
{
  constexpr int K = KTILES * 64;
  __shared__ __align__(16) u16 Asl[64 * 72];
  __shared__ __align__(16) u16 Bsl[64 * 72];
  const int tid = threadIdx.x;
  const int w = tid >> 6, lane = tid & 63, lm = lane & 15, quad = lane >> 4;
  const size_t m0 = (size_t)blockIdx.y * 64, n0 = (size_t)blockIdx.x * 64;

  f32x4 acc[4];
#pragma unroll
  for (int nt = 0; nt < 4; ++nt) { f32x4 z = {0.f, 0.f, 0.f, 0.f}; acc[nt] = z; }

  for (int kb = 0; kb < KTILES; ++kb) {
    if (AF32) {
      const float* Af = (const float*)Av;
#pragma unroll
      for (int c = 0; c < 4; ++c) {
        int idx = c * 256 + tid;
        int row = idx >> 4, k4 = idx & 15;
        float4 v = *(const float4*)(Af + (m0 + row) * (size_t)K + kb * 64 + k4 * 4);
        u64 pv = (u64)f2bf(v.x) | ((u64)f2bf(v.y) << 16) |
                 ((u64)f2bf(v.z) << 32) | ((u64)f2bf(v.w) << 48);
        *(u64*)(&Asl[row * 72 + k4 * 4]) = pv;
      }
    } else {
      const u16* Ab = (const u16*)Av;
#pragma unroll
      for (int c = 0; c < 2; ++c) {
        int idx = c * 256 + tid;
        int row = idx >> 3, k8 = idx & 7;
        *(uint4*)(&Asl[row * 72 + k8 * 8]) =
            *(const uint4*)(Ab + (m0 + row) * (size_t)K + kb * 64 + k8 * 8);
      }
    }
#pragma unroll
    for (int c = 0; c < 2; ++c) {
      int idx = c * 256 + tid;
      int row = idx >> 3, k8 = idx & 7;
      *(uint4*)(&Bsl[row * 72 + k8 * 8]) =
          *(const uint4*)(B + (n0 + row) * (size_t)K + kb * 64 + k8 * 8);
    }
    __syncthreads();
#pragma unroll
    for (int kc = 0; kc < 2; ++kc) {
      short8 a = *(const short8*)(&Asl[(w * 16 + lm) * 72 + kc * 32 + quad * 8]);
#pragma unroll
      for (int nt = 0; nt < 4; ++nt) {
        short8 b = *(const short8*)(&Bsl[(nt * 16 + lm) * 72 + kc * 32 + quad * 8]);
        acc[nt] = __builtin_amdgcn_mfma_f32_16x16x32_bf16(a, b, acc[nt], 0, 0, 0);
      }
    }
    __syncthreads();
  }
#pragma unroll
  for (int nt = 0; nt < 4; ++nt) {
    size_t n = n0 + nt * 16 + lm;
    float bn = (BMODE == 1) ? bias[n] : 0.f;
#pragma unroll
    for (int r = 0; r < 4; ++r) {
      size_t m = m0 + w * 16 + quad * 4 + r;
      float v = acc[nt][r] + ((BMODE == 2) ? bias[m] : bn);
      if (OUTBF) ((u16*)Cv)[m * ldc + n] = f2bf(v);
      else       ((float*)Cv)[m * ldc + n] = v;
    }
  }
}

// ---------------- LSTM recurrence (gates^T orientation, no LDS) ----------------
__global__ __launch_bounds__(256, 1) void lstm_rec(
    const u16* __restrict__ xg2,   // [CN][1024] row' layout
    const u16* __restrict__ whh,   // frag-packed per (q,w): 16384 u16
    u16* __restrict__ xout,        // [CN][256]
    u16* __restrict__ hx,          // [2 parity][64 b][256 j]
    int* __restrict__ flags,       // [4] monotone absolute-step counters
    float* __restrict__ cstb,      // [1024 threads][16] persisted c-state
    int base)
{
  const int q = blockIdx.x, tid = threadIdx.x;
  const int w = tid >> 6, lane = tid & 63, lm = lane & 15, quad = lane >> 4;

  // W_hh fragments, 128 VGPRs/lane
  short8 wf[4][8];
  {
    const u16* wq = whh + (size_t)(q * 4 + w) * 16384 + lane * 8;
#pragma unroll
    for (int t = 0; t < 4; ++t)
#pragma unroll
      for (int kc = 0; kc < 8; ++kc)
        wf[t][kc] = *(const short8*)(wq + (t * 8 + kc) * 512);
  }

  float* cp = cstb + (size_t)(q * 256 + tid) * 16;
  f32x4 cst[4];                       // cst[t][nt]
  if (base) {
#pragma unroll
    for (int t = 0; t < 4; ++t) cst[t] = ((const f32x4*)cp)[t];
  } else {
#pragma unroll
    for (int t = 0; t < 4; ++t) { f32x4 z = {0.f, 0.f, 0.f, 0.f}; cst[t] = z; }
  }

  const int jcol = q * 64 + w * 16 + quad * 4;   // publish column base (4 consecutive j)

  for (int s = 1; s <= CS; ++s) {
    const int sA = base + s;
    // ---- acc init from xg2 (one u64 per acc: 4 gate rows, contiguous) ----
    f32x4 acc[4][4];
#pragma unroll
    for (int t = 0; t < 4; ++t)
#pragma unroll
      for (int nt = 0; nt < 4; ++nt) {
        u64 xv = *(const u64*)(xg2 + ((size_t)(s - 1) * 64 + nt * 16 + lm) * 1024
                               + q * 256 + (w * 4 + t) * 16 + quad * 4);
        f32x4 tt = { bf2f((u16)xv), bf2f((u16)(xv >> 16)),
                     bf2f((u16)(xv >> 32)), bf2f((u16)(xv >> 48)) };
        acc[t][nt] = tt;
      }
    // ---- wait for peers, then gates += W_hh * h (B-frags straight from hx) ----
    if (sA >= 2) {
      if (tid < 4) {
        while (__hip_atomic_load(&flags[tid], __ATOMIC_RELAXED, __HIP_MEMORY_SCOPE_AGENT)
               < sA - 1) { }
      }
      __syncthreads();
      const u16* hsrc = hx + (size_t)((sA - 1) & 1) * 16384;
#pragma unroll
      for (int kc = 0; kc < 8; ++kc) {
        short8 bf4[4];
#pragma unroll
        for (int nt = 0; nt < 4; ++nt) {
          const u16* hp = hsrc + (size_t)(nt * 16 + lm) * 256 + kc * 32 + quad * 8;
          union { u64 v[2]; short8 s8; } uu;
          uu.v[0] = __hip_atomic_load((const u64*)hp, __ATOMIC_RELAXED, __HIP_MEMORY_SCOPE_AGENT);
          uu.v[1] = __hip_atomic_load((const u64*)(hp + 4), __ATOMIC_RELAXED, __HIP_MEMORY_SCOPE_AGENT);
          bf4[nt] = uu.s8;
        }
#pragma unroll
        for (int t = 0; t < 4; ++t)
#pragma unroll
          for (int nt = 0; nt < 4; ++nt)
            acc[t][nt] = __builtin_amdgcn_mfma_f32_16x16x32_bf16(wf[t][kc], bf4[nt], acc[t][nt], 0, 0, 0);
      }
    }
    // ---- nonlinearity: each acc's components are (i,f,g,o) of one (j,b) ----
    u64 hv[4] = {0, 0, 0, 0};
#pragma unroll
    for (int t = 0; t < 4; ++t)
#pragma unroll
      for (int nt = 0; nt < 4; ++nt) {
        float iv = sigf(acc[t][nt][0]);
        float fv = sigf(acc[t][nt][1]);
        float gv = tanhf_fast(acc[t][nt][2]);
        float ov = sigf(acc[t][nt][3]);
        float cv = fv * cst[t][nt] + iv * gv;
        cst[t][nt] = cv;
        hv[nt] |= (u64)f2bf(ov * tanhf_fast(cv)) << (16 * t);
      }
    // ---- publish: u64 atomics to hx + plain u64 to xout ----
    u16* hdst = hx + (size_t)(sA & 1) * 16384;
#pragma unroll
    for (int nt = 0; nt < 4; ++nt) {
      int b = nt * 16 + lm;
      __hip_atomic_store((u64*)(hdst + (size_t)b * 256 + jcol), hv[nt],
                         __ATOMIC_RELAXED, __HIP_MEMORY_SCOPE_AGENT);
      *(u64*)(xout + ((size_t)(s - 1) * 64 + b) * 256 + jcol) = hv[nt];
    }
    __syncthreads();   // all waves drain vmcnt before flag
    if (tid == 0)
      __hip_atomic_store(&flags[q], sA, __ATOMIC_RELAXED, __HIP_MEMORY_SCOPE_AGENT);
  }
#pragma unroll
  for (int t = 0; t < 4; ++t) ((f32x4*)cp)[t] = cst[t];
}

// ---------------- launch ----------------
extern "C" void kernel_launch(void* const* d_in, const int* in_sizes, int n_in,
                              void* d_out, int out_size, void* d_ws, size_t ws_size,
                              hipStream_t stream)
{
  const float* in0   = (const float*)d_in[0];
  const float* enc_w = (const float*)d_in[1];
  const float* enc_b = (const float*)d_in[2];
  const float* w_ih  = (const float*)d_in[3];
  const float* w_hh  = (const float*)d_in[4];
  const float* b_ih  = (const float*)d_in[5];
  const float* b_hh  = (const float*)d_in[6];
  const float* dec_w = (const float*)d_in[7];
  const float* dec_b = (const float*)d_in[8];

  char* ws = (char*)d_ws;
  u16*   XG    = (u16*)(ws);                 // 33,554,432 B  xg chunk [CN][1024]
  u16*   XA    = (u16*)(ws + 33554432);      //  8,388,608 B  x chunk stream A
  u16*   XB    = (u16*)(ws + 41943040);      //  8,388,608 B  x chunk stream B
  u16*   WIH   = (u16*)(ws + 50331648);      //  1,048,576 B  [l][row'][k]
  u16*   WHH   = (u16*)(ws + 51380224);      //  1,048,576 B  frag pack
  u16*   WENC  = (u16*)(ws + 52428800);      //     32,768 B
  u16*   WDEC  = (u16*)(ws + 52461568);      //     32,768 B
  float* BIAS2 = (float*)(ws + 52494336);    //      8,192 B
  u16*   HX    = (u16*)(ws + 52502528);      //    131,072 B (2 layers x 65536)
  float* CST   = (float*)(ws + 52633600);    //    131,072 B (2 layers x 65536)
  int*   FLAGS = (int*)(ws + 52764672);      //         64 B

  if (ws_size < 52764736) return;   // diagnostic guard

  prep_kernel<<<dim3((PREP_TOTAL + 255) / 256), 256, 0, stream>>>(
      enc_w, w_ih, w_hh, b_ih, b_hh, dec_w,
      WENC, WDEC, WIH, BIAS2, WHH, FLAGS);

  for (int c = 0; c < NCH; ++c) {
    const float* inc = in0 + (size_t)c * CN * 64;
    float* outc = (float*)d_out + (size_t)c * CN * 64;
    // encoder: x0c = inc @ enc_w^T + enc_b   (M=CN, N=256, K=64)
    gemm_bt<1, 1, 1, 1><<<dim3(4, CN / 64), 256, 0, stream>>>(inc, WENC, XA, enc_b, 256);
    // layer 0: xg2 = x0c @ WIH0'^T + bias2   (M=CN, N=1024, K=256)
    gemm_bt<4, 1, 1, 0><<<dim3(16, CN / 64), 256, 0, stream>>>(XA, WIH, XG, BIAS2, 1024);
    lstm_rec<<<dim3(4), 256, 0, stream>>>(XG, WHH, XB, HX, FLAGS, CST, c * CS);
    // layer 1
    gemm_bt<4, 1, 1, 0><<<dim3(16, CN / 64), 256, 0, stream>>>(XB, WIH + 262144, XG, BIAS2 + 1024, 1024);
    lstm_rec<<<dim3(4), 256, 0, stream>>>(XG, WHH + 262144, XA, HX + 32768, FLAGS + 4, CST + 16384, c * CS);
    // decoder: outc = x2c @ dec_w^T + dec_b  (M=CN, N=64, K=256), fp32 out
    gemm_bt<4, 0, 1, 0><<<dim3(1, CN / 64), 256, 0, stream>>>(XA, WDEC, (void*)outc, dec_b, 64);
  }

  (void)in_sizes; (void)n_in; (void)out_size;
}

// Round 5
// 13002.045 us; speedup vs baseline: 4.0212x; 4.0212x over previous
//
#include <hip/hip_runtime.h>

// LSTM_15556371546645 — MI355X (gfx950), round 5
// R4 structure, R2/R3-proven synchronization:
// - Both LSTM layers fused in ONE kernel per chunk, pipelined (layer 1 lags
//   layer 0 by one step; W_ih1*h0 via a second MFMA chain, fp32-accumulated).
// - 16 workgroups: layer (2) x gate-row quarter p (4) x batch half n2 (2).
//   NO election, grid=16: all exchange is AGENT-scope atomic load/store
//   (MALL-executing, placement-independent — HW-verified correct in R2/R3).
// - h exchange: depth-4 ring buffers [4][64 b][256 j]; one-thread-per-flag
//   polls; coalesced u64 gather staged into padded LDS; MFMA B-frags via
//   ds_read_b128.
// - Encoder GEMM folded into layer-0 input GEMM (CW = W_ih0 . enc_w, K=64).

typedef unsigned short u16;
typedef unsigned long long u64;
typedef __attribute__((ext_vector_type(8))) short short8;   // 8 x bf16
typedef __attribute__((ext_vector_type(4))) float f32x4;    // MFMA acc

#define SEQ  2048
#define CS   256            // chunk steps
#define NCH  (SEQ / CS)     // 8 chunks
#define CN   (CS * 64)      // rows per chunk = 16384

// ---------------- numeric helpers ----------------
__device__ __forceinline__ u16 f2bf(float f) {
  unsigned u = __float_as_uint(f);
  unsigned r = u + 0x7fffu + ((u >> 16) & 1u);   // RTNE
  return (u16)(r >> 16);
}
__device__ __forceinline__ float bf2f(u16 h) {
  return __uint_as_float(((unsigned)h) << 16);
}
__device__ __forceinline__ float sigf(float x) {
  return __builtin_amdgcn_rcpf(1.f + __expf(-x));
}
__device__ __forceinline__ float tanhf_fast(float x) {
  return 1.f - 2.f * __builtin_amdgcn_rcpf(1.f + __expf(2.f * x));
}

// Row permutation: row' = p*256 + T*16 + u (T=0..15,u=0..15)
// gate g=u&3; j=(T>>2)*16+((u>>2)<<2)+(T&3); r_orig=g*256+p*64+j  [HW-verified R3]
__device__ __forceinline__ int rowp_to_orig(int rowp) {
  int p = rowp >> 8, T = (rowp >> 4) & 15, u = rowp & 15;
  int g = u & 3;
  int j = ((T >> 2) << 4) + ((u >> 2) << 2) + (T & 3);
  return g * 256 + p * 64 + j;
}

// ---------------- prep ----------------
// P0 16384  : dec_w -> bf16
// P1 65536  : CW[row'][f] = sum_k W_ih0[r][k]*enc_w[k][f]      (bf16)
// P2 1024   : CB[row'] = sum_k W_ih0[r][k]*enc_b[k] + b_ih0[r]+b_hh0[r]
// P3 1024   : B1P[row'] = b_ih1[r]+b_hh1[r]
// P4 524288 : W_hh frag pack (l=0,1)   [HW-verified layout, R3]
// P5 262144 : W_ih1 frag pack (same layout)
// P6 16     : zero FLAGS
#define PREP_TOTAL (16384 + 65536 + 1024 + 1024 + 524288 + 262144 + 16)

__global__ void prep_kernel(const float* __restrict__ enc_w, const float* __restrict__ enc_b,
                            const float* __restrict__ w_ih, const float* __restrict__ w_hh,
                            const float* __restrict__ b_ih, const float* __restrict__ b_hh,
                            const float* __restrict__ dec_w,
                            u16* __restrict__ WDEC, u16* __restrict__ CW,
                            float* __restrict__ CB, float* __restrict__ B1P,
                            u16* __restrict__ WHHP, u16* __restrict__ WIH1P,
                            int* __restrict__ ZERO)
{
  size_t idx = (size_t)blockIdx.x * 256 + threadIdx.x;
  if (idx < 16384) { WDEC[idx] = f2bf(dec_w[idx]); return; }
  idx -= 16384;
  if (idx < 65536) {
    int rowp = (int)(idx >> 6), f = (int)(idx & 63);
    int r = rowp_to_orig(rowp);
    float a = 0.f;
    for (int k = 0; k < 256; ++k) a += w_ih[r * 256 + k] * enc_w[k * 64 + f];
    CW[idx] = f2bf(a);
    return;
  }
  idx -= 65536;
  if (idx < 1024) {
    int r = rowp_to_orig((int)idx);
    float a = b_ih[r] + b_hh[r];
    for (int k = 0; k < 256; ++k) a += w_ih[r * 256 + k] * enc_b[k];
    CB[idx] = a;
    return;
  }
  idx -= 1024;
  if (idx < 1024) {
    int r = rowp_to_orig((int)idx);
    B1P[idx] = b_ih[1024 + r] + b_hh[1024 + r];
    return;
  }
  idx -= 1024;
  if (idx < 524288) {   // WHHP: flat = ((((l*4+p)*4+w)*4+t)*8+kc)*512 + lane*8 + e
    int l = (int)(idx >> 18);
    int rem = (int)(idx & 262143);
    int e = rem & 7, lane = (rem >> 3) & 63, kc = (rem >> 9) & 7;
    int t = (rem >> 12) & 3, wv = (rem >> 14) & 3, pp = (rem >> 16) & 3;
    int u = lane & 15, qd = lane >> 4;
    int g = u & 3;
    int j = wv * 16 + ((u >> 2) << 2) + t;
    int r = g * 256 + pp * 64 + j;
    int k = kc * 32 + qd * 8 + e;
    WHHP[idx] = f2bf(w_hh[(size_t)l * 262144 + (size_t)r * 256 + k]);
    return;
  }
  idx -= 524288;
  if (idx < 262144) {   // WIH1P (l=1)
    int rem = (int)idx;
    int e = rem & 7, lane = (rem >> 3) & 63, kc = (rem >> 9) & 7;
    int t = (rem >> 12) & 3, wv = (rem >> 14) & 3, pp = (rem >> 16) & 3;
    int u = lane & 15, qd = lane >> 4;
    int g = u & 3;
    int j = wv * 16 + ((u >> 2) << 2) + t;
    int r = g * 256 + pp * 64 + j;
    int k = kc * 32 + qd * 8 + e;
    WIH1P[idx] = f2bf(w_ih[262144 + (size_t)r * 256 + k]);
    return;
  }
  idx -= 262144;
  if (idx < 16) ZERO[idx] = 0;
}

// ---------------- generic bf16 GEMM:  C(MxN) = A(MxK) * B(NxK)^T + bias ----------------
template<int KTILES, int OUTBF, int BMODE, int AF32>
__global__ __launch_bounds__(256, 1) void gemm_bt(
    const void* __restrict__ Av, const u16* __restrict__ B, void* __restrict__ Cv,
    const float* __restrict__ bias, size_t ldc)
{
  constexpr int K = KTILES * 64;
  __shared__ __align__(16) u16 Asl[64 * 72];
  __shared__ __align__(16) u16 Bsl[64 * 72];
  const int tid = threadIdx.x;
  const int w = tid >> 6, lane = tid & 63, lm = lane & 15, quad = lane >> 4;
  const size_t m0 = (size_t)blockIdx.y * 64, n0 = (size_t)blockIdx.x * 64;

  f32x4 acc[4];
#pragma unroll
  for (int nt = 0; nt < 4; ++nt) { f32x4 z = {0.f, 0.f, 0.f, 0.f}; acc[nt] = z; }

  for (int kb = 0; kb < KTILES; ++kb) {
    if (AF32) {
      const float* Af = (const float*)Av;
#pragma unroll
      for (int c = 0; c < 4; ++c) {
        int idx = c * 256 + tid;
        int row = idx >> 4, k4 = idx & 15;
        float4 v = *(const float4*)(Af + (m0 + row) * (size_t)K + kb * 64 + k4 * 4);
        u64 pv = (u64)f2bf(v.x) | ((u64)f2bf(v.y) << 16) |
                 ((u64)f2bf(v.z) << 32) | ((u64)f2bf(v.w) << 48);
        *(u64*)(&Asl[row * 72 + k4 * 4]) = pv;
      }
    } else {
      const u16* Ab = (const u16*)Av;
#pragma unroll
      for (int c = 0; c < 2; ++c) {
        int idx = c * 256 + tid;
        int row = idx >> 3, k8 = idx & 7;
        *(uint4*)(&Asl[row * 72 + k8 * 8]) =
            *(const uint4*)(Ab + (m0 + row) * (size_t)K + kb * 64 + k8 * 8);
      }
    }
#pragma unroll
    for (int c = 0; c < 2; ++c) {
      int idx = c * 256 + tid;
      int row = idx >> 3, k8 = idx & 7;
      *(uint4*)(&Bsl[row * 72 + k8 * 8]) =
          *(const uint4*)(B + (n0 + row) * (size_t)K + kb * 64 + k8 * 8);
    }
    __syncthreads();
#pragma unroll
    for (int kc = 0; kc < 2; ++kc) {
      short8 a = *(const short8*)(&Asl[(w * 16 + lm) * 72 + kc * 32 + quad * 8]);
#pragma unroll
      for (int nt = 0; nt < 4; ++nt) {
        short8 b = *(const short8*)(&Bsl[(nt * 16 + lm) * 72 + kc * 32 + quad * 8]);
        acc[nt] = __builtin_amdgcn_mfma_f32_16x16x32_bf16(a, b, acc[nt], 0, 0, 0);
      }
    }
    __syncthreads();
  }
#pragma unroll
  for (int nt = 0; nt < 4; ++nt) {
    size_t n = n0 + nt * 16 + lm;
    float bn = (BMODE == 1) ? bias[n] : 0.f;
#pragma unroll
    for (int r = 0; r < 4; ++r) {
      size_t m = m0 + w * 16 + quad * 4 + r;
      float v = acc[nt][r] + ((BMODE == 2) ? bias[m] : bn);
      if (OUTBF) ((u16*)Cv)[m * ldc + n] = f2bf(v);
      else       ((float*)Cv)[m * ldc + n] = v;
    }
  }
}

// ---------------- fused 2-layer pipelined recurrence (16 wgs, agent scope) ----------------
// role = blockIdx.x: layer = role>>3, p = role&3, n2 = (role>>2)&1.
// flags[0..7]=layer0 (n2*4+p), flags[8..15]=layer1. hx rings: [4][64 b][256 j].
__global__ __launch_bounds__(256, 1) void lstm_fused(
    const u16* __restrict__ xg0, u16* __restrict__ x2,
    const u16* __restrict__ whhp, const u16* __restrict__ wih1p,
    const float* __restrict__ b1p,
    u16* __restrict__ hx0, u16* __restrict__ hx1,
    int* __restrict__ flags, float* __restrict__ cstb, int base)
{
  __shared__ __align__(16) u16 Hl[2][32 * 264];   // +8 u16 row pad
  const int tid = threadIdx.x;
  const int role = blockIdx.x;
  const int layer = role >> 3, p = role & 3, n2 = (role >> 2) & 1;
  const int lane = tid & 63, w = tid >> 6, lm = lane & 15, quad = lane >> 4;

  // ---- weights into VGPR fragments ----
  short8 wfh[4][8], wfi[4][8];
  {
    const u16* wp = whhp + (size_t)((layer * 4 + p) * 4 + w) * 16384 + lane * 8;
#pragma unroll
    for (int t = 0; t < 4; ++t)
#pragma unroll
      for (int kc = 0; kc < 8; ++kc)
        wfh[t][kc] = *(const short8*)(wp + (t * 8 + kc) * 512);
  }
  f32x4 bias_f[4];
  if (layer) {
    const u16* wp = wih1p + (size_t)(p * 4 + w) * 16384 + lane * 8;
#pragma unroll
    for (int t = 0; t < 4; ++t)
#pragma unroll
      for (int kc = 0; kc < 8; ++kc)
        wfi[t][kc] = *(const short8*)(wp + (t * 8 + kc) * 512);
#pragma unroll
    for (int t = 0; t < 4; ++t)
      bias_f[t] = *(const f32x4*)(b1p + p * 256 + (w * 4 + t) * 16 + quad * 4);
  }

  float* cp = cstb + (size_t)(((layer * 4 + p) * 2 + n2) * 256 + tid) * 8;
  float cst[4][2];
  if (base) {
#pragma unroll
    for (int t = 0; t < 4; ++t) { cst[t][0] = cp[t * 2]; cst[t][1] = cp[t * 2 + 1]; }
  } else {
#pragma unroll
    for (int t = 0; t < 4; ++t) { cst[t][0] = 0.f; cst[t][1] = 0.f; }
  }

  int* myflag = flags + layer * 8 + n2 * 4 + p;
  int* gA = flags + n2 * 4;        // layer-0 flag group (same batch half)
  int* gB = flags + 8 + n2 * 4;    // layer-1 flag group (same batch half)
  const int jcol = p * 64 + w * 16 + quad * 4;
  u16* myhx = layer ? hx1 : hx0;

  for (int s = 1; s <= CS; ++s) {
    const int sA = base + s;
    // xg0 loads early (layer 0) to overlap with the poll
    u64 xv[4][2];
    if (layer == 0) {
#pragma unroll
      for (int t = 0; t < 4; ++t)
#pragma unroll
        for (int nt = 0; nt < 2; ++nt)
          xv[t][nt] = *(const u64*)(xg0 +
              ((size_t)(s - 1) * 64 + n2 * 32 + nt * 16 + lm) * 1024 +
              p * 256 + (w * 4 + t) * 16 + quad * 4);
    }
    // ---- flag polls: one thread per flag, agent-scope atomic loads ----
    const int needA = layer ? sA : sA - 1;        // layer-0 group requirement
    const int needB = layer ? sA - 1 : sA - 4;    // layer-1 group requirement
    if (tid < 8) {
      int* fp = (tid < 4) ? (gA + tid) : (gB + (tid - 4));
      const int need = (tid < 4) ? needA : needB;
      if (need > 0) {
        while (__hip_atomic_load(fp, __ATOMIC_RELAXED, __HIP_MEMORY_SCOPE_AGENT)
               < need) { }
      }
    }
    __syncthreads();
    // ---- coalesced gather -> LDS (agent-scope u64 atomic loads) ----
    if (layer == 0) {
      if (sA >= 2) {
        const u16* src = hx0 + (size_t)((sA - 1) & 3) * 16384;
#pragma unroll
        for (int i = 0; i < 8; ++i) {
          int fi = i * 256 + tid, lb = fi >> 6, j4 = fi & 63;
          u64 v = __hip_atomic_load(
              (const u64*)(src + ((size_t)(n2 * 32 + lb) * 256 + j4 * 4)),
              __ATOMIC_RELAXED, __HIP_MEMORY_SCOPE_AGENT);
          *(u64*)(&Hl[0][lb * 264 + j4 * 4]) = v;
        }
      }
    } else {
      const u16* s0 = hx0 + (size_t)(sA & 3) * 16384;
#pragma unroll
      for (int i = 0; i < 8; ++i) {
        int fi = i * 256 + tid, lb = fi >> 6, j4 = fi & 63;
        u64 v = __hip_atomic_load(
            (const u64*)(s0 + ((size_t)(n2 * 32 + lb) * 256 + j4 * 4)),
            __ATOMIC_RELAXED, __HIP_MEMORY_SCOPE_AGENT);
        *(u64*)(&Hl[0][lb * 264 + j4 * 4]) = v;
      }
      if (sA >= 2) {
        const u16* s1 = hx1 + (size_t)((sA - 1) & 3) * 16384;
#pragma unroll
        for (int i = 0; i < 8; ++i) {
          int fi = i * 256 + tid, lb = fi >> 6, j4 = fi & 63;
          u64 v = __hip_atomic_load(
              (const u64*)(s1 + ((size_t)(n2 * 32 + lb) * 256 + j4 * 4)),
              __ATOMIC_RELAXED, __HIP_MEMORY_SCOPE_AGENT);
          *(u64*)(&Hl[1][lb * 264 + j4 * 4]) = v;
        }
      }
    }
    __syncthreads();
    // ---- acc init ----
    f32x4 acc[4][2];
    if (layer == 0) {
#pragma unroll
      for (int t = 0; t < 4; ++t)
#pragma unroll
        for (int nt = 0; nt < 2; ++nt) {
          u64 v = xv[t][nt];
          f32x4 tt = { bf2f((u16)v), bf2f((u16)(v >> 16)),
                       bf2f((u16)(v >> 32)), bf2f((u16)(v >> 48)) };
          acc[t][nt] = tt;
        }
    } else {
#pragma unroll
      for (int t = 0; t < 4; ++t)
#pragma unroll
        for (int nt = 0; nt < 2; ++nt) acc[t][nt] = bias_f[t];
    }
    // ---- MFMA chains ----
    if (layer == 0) {
      if (sA >= 2) {
#pragma unroll
        for (int kc = 0; kc < 8; ++kc) {
          short8 b0[2];
#pragma unroll
          for (int nt = 0; nt < 2; ++nt)
            b0[nt] = *(const short8*)(&Hl[0][(nt * 16 + lm) * 264 + kc * 32 + quad * 8]);
#pragma unroll
          for (int t = 0; t < 4; ++t)
#pragma unroll
            for (int nt = 0; nt < 2; ++nt)
              acc[t][nt] = __builtin_amdgcn_mfma_f32_16x16x32_bf16(
                  wfh[t][kc], b0[nt], acc[t][nt], 0, 0, 0);
        }
      }
    } else {
#pragma unroll
      for (int kc = 0; kc < 8; ++kc) {
        short8 b0[2];
#pragma unroll
        for (int nt = 0; nt < 2; ++nt)
          b0[nt] = *(const short8*)(&Hl[0][(nt * 16 + lm) * 264 + kc * 32 + quad * 8]);
#pragma unroll
        for (int t = 0; t < 4; ++t)
#pragma unroll
          for (int nt = 0; nt < 2; ++nt)
            acc[t][nt] = __builtin_amdgcn_mfma_f32_16x16x32_bf16(
                wfi[t][kc], b0[nt], acc[t][nt], 0, 0, 0);
      }
      if (sA >= 2) {
#pragma unroll
        for (int kc = 0; kc < 8; ++kc) {
          short8 b1[2];
#pragma unroll
          for (int nt = 0; nt < 2; ++nt)
            b1[nt] = *(const short8*)(&Hl[1][(nt * 16 + lm) * 264 + kc * 32 + quad * 8]);
#pragma unroll
          for (int t = 0; t < 4; ++t)
#pragma unroll
            for (int nt = 0; nt < 2; ++nt)
              acc[t][nt] = __builtin_amdgcn_mfma_f32_16x16x32_bf16(
                  wfh[t][kc], b1[nt], acc[t][nt], 0, 0, 0);
        }
      }
    }
    // ---- nonlinearity: acc[t][nt] = (i,f,g,o) of (j = jcol+t, b) ----
    u64 hv[2] = {0, 0};
#pragma unroll
    for (int t = 0; t < 4; ++t)
#pragma unroll
      for (int nt = 0; nt < 2; ++nt) {
        float iv = sigf(acc[t][nt][0]);
        float fv = sigf(acc[t][nt][1]);
        float gv = tanhf_fast(acc[t][nt][2]);
        float ov = sigf(acc[t][nt][3]);
        float cv = fv * cst[t][nt] + iv * gv;
        cst[t][nt] = cv;
        hv[nt] |= (u64)f2bf(ov * tanhf_fast(cv)) << (16 * t);
      }
    // ---- publish: agent-scope u64 atomic stores to hx ring ----
    u16* hd = myhx + (size_t)(sA & 3) * 16384;
#pragma unroll
    for (int nt = 0; nt < 2; ++nt) {
      int b = n2 * 32 + nt * 16 + lm;
      __hip_atomic_store((u64*)(hd + (size_t)b * 256 + jcol), hv[nt],
                         __ATOMIC_RELAXED, __HIP_MEMORY_SCOPE_AGENT);
      if (layer)
        *(u64*)(x2 + ((size_t)(s - 1) * 64 + b) * 256 + jcol) = hv[nt];
    }
    __syncthreads();   // vmcnt(0) drain: data globally visible before flag
    if (tid == 0)
      __hip_atomic_store(myflag, sA, __ATOMIC_RELAXED, __HIP_MEMORY_SCOPE_AGENT);
  }
#pragma unroll
  for (int t = 0; t < 4; ++t) { cp[t * 2] = cst[t][0]; cp[t * 2 + 1] = cst[t][1]; }
}

// ---------------- launch ----------------
extern "C" void kernel_launch(void* const* d_in, const int* in_sizes, int n_in,
                              void* d_out, int out_size, void* d_ws, size_t ws_size,
                              hipStream_t stream)
{
  const float* in0   = (const float*)d_in[0];
  const float* enc_w = (const float*)d_in[1];
  const float* enc_b = (const float*)d_in[2];
  const float* w_ih  = (const float*)d_in[3];
  const float* w_hh  = (const float*)d_in[4];
  const float* b_ih  = (const float*)d_in[5];
  const float* b_hh  = (const float*)d_in[6];
  const float* dec_w = (const float*)d_in[7];
  const float* dec_b = (const float*)d_in[8];

  char* ws = (char*)d_ws;
  u16*   XG    = (u16*)(ws);                 // 33,554,432  xg0 chunk [CN][1024]
  u16*   X2    = (u16*)(ws + 33554432);      //  8,388,608  x2 chunk [CN][256]
  u16*   WHHP  = (u16*)(ws + 41943040);      //  1,048,576
  u16*   WIH1P = (u16*)(ws + 42991616);      //    524,288
  u16*   CW    = (u16*)(ws + 43515904);      //    131,072
  u16*   WDEC  = (u16*)(ws + 43646976);      //     32,768
  float* CB    = (float*)(ws + 43679744);    //      4,096
  float* B1P   = (float*)(ws + 43683840);    //      4,096
  u16*   HX0   = (u16*)(ws + 43687936);      //    131,072  ring 4 x 32KB
  u16*   HX1   = (u16*)(ws + 43819008);      //    131,072
  float* CST   = (float*)(ws + 43950080);    //    131,072
  int*   FLAGS = (int*)(ws + 44081152);      //         64

  if (ws_size < 44081216) return;   // diagnostic guard

  prep_kernel<<<dim3((PREP_TOTAL + 255) / 256), 256, 0, stream>>>(
      enc_w, enc_b, w_ih, w_hh, b_ih, b_hh, dec_w,
      WDEC, CW, CB, B1P, WHHP, WIH1P, FLAGS);

  for (int c = 0; c < NCH; ++c) {
    const float* inc = in0 + (size_t)c * CN * 64;
    float* outc = (float*)d_out + (size_t)c * CN * 64;
    // xg0 = inc @ CW^T + CB  (encoder folded in; M=CN, N=1024, K=64)
    gemm_bt<1, 1, 1, 1><<<dim3(16, CN / 64), 256, 0, stream>>>(inc, CW, XG, CB, 1024);
    // fused pipelined 2-layer recurrence
    lstm_fused<<<dim3(16), 256, 0, stream>>>(XG, X2, WHHP, WIH1P, B1P,
                                             HX0, HX1, FLAGS, CST, c * CS);
    // decoder: outc = x2 @ dec_w^T + dec_b  (M=CN, N=64, K=256), fp32 out
    gemm_bt<4, 0, 1, 0><<<dim3(1, CN / 64), 256, 0, stream>>>(X2, WDEC, (void*)outc, dec_b, 64);
  }

  (void)in_sizes; (void)n_in; (void)out_size;
}

// Round 6
// 12087.454 us; speedup vs baseline: 4.3254x; 1.0757x over previous
//
#include <hip/hip_runtime.h>

// LSTM_15556371546645 — MI355X (gfx950), round 6
// R5 structure (fused pipelined 2-layer recurrence, 16 wgs, agent-scope
// exchange) + three critical-path fixes:
//  (a) flags padded to 256 B each (kill MALL cacheline contention),
//  (b) register-cached monotone flag polls (most polls become free; L1 can
//      stream behind L0 without an observe-RT per step),
//  (c) publish order: hx stores -> barrier(vmcnt drain) -> flag -> x2 stores
//      (x2 HBM write-back off the critical path; stream order covers decoder).

typedef unsigned short u16;
typedef unsigned long long u64;
typedef __attribute__((ext_vector_type(8))) short short8;   // 8 x bf16
typedef __attribute__((ext_vector_type(4))) float f32x4;    // MFMA acc

#define SEQ  2048
#define CS   256            // chunk steps
#define NCH  (SEQ / CS)     // 8 chunks
#define CN   (CS * 64)      // rows per chunk = 16384

// ---------------- numeric helpers ----------------
__device__ __forceinline__ u16 f2bf(float f) {
  unsigned u = __float_as_uint(f);
  unsigned r = u + 0x7fffu + ((u >> 16) & 1u);   // RTNE
  return (u16)(r >> 16);
}
__device__ __forceinline__ float bf2f(u16 h) {
  return __uint_as_float(((unsigned)h) << 16);
}
__device__ __forceinline__ float sigf(float x) {
  return __builtin_amdgcn_rcpf(1.f + __expf(-x));
}
__device__ __forceinline__ float tanhf_fast(float x) {
  return 1.f - 2.f * __builtin_amdgcn_rcpf(1.f + __expf(2.f * x));
}

// Row permutation: row' = p*256 + T*16 + u (T=0..15,u=0..15)
// gate g=u&3; j=(T>>2)*16+((u>>2)<<2)+(T&3); r_orig=g*256+p*64+j  [HW-verified R3]
__device__ __forceinline__ int rowp_to_orig(int rowp) {
  int p = rowp >> 8, T = (rowp >> 4) & 15, u = rowp & 15;
  int g = u & 3;
  int j = ((T >> 2) << 4) + ((u >> 2) << 2) + (T & 3);
  return g * 256 + p * 64 + j;
}

// ---------------- prep ----------------
// P0 16384  : dec_w -> bf16
// P1 65536  : CW[row'][f] = sum_k W_ih0[r][k]*enc_w[k][f]      (bf16)
// P2 1024   : CB[row'] = sum_k W_ih0[r][k]*enc_b[k] + b_ih0[r]+b_hh0[r]
// P3 1024   : B1P[row'] = b_ih1[r]+b_hh1[r]
// P4 524288 : W_hh frag pack (l=0,1)   [HW-verified layout, R3]
// P5 262144 : W_ih1 frag pack (same layout)
// P6 1024   : zero FLAGS (16 flags x 64-int padding)
#define PREP_TOTAL (16384 + 65536 + 1024 + 1024 + 524288 + 262144 + 1024)

__global__ void prep_kernel(const float* __restrict__ enc_w, const float* __restrict__ enc_b,
                            const float* __restrict__ w_ih, const float* __restrict__ w_hh,
                            const float* __restrict__ b_ih, const float* __restrict__ b_hh,
                            const float* __restrict__ dec_w,
                            u16* __restrict__ WDEC, u16* __restrict__ CW,
                            float* __restrict__ CB, float* __restrict__ B1P,
                            u16* __restrict__ WHHP, u16* __restrict__ WIH1P,
                            int* __restrict__ ZERO)
{
  size_t idx = (size_t)blockIdx.x * 256 + threadIdx.x;
  if (idx < 16384) { WDEC[idx] = f2bf(dec_w[idx]); return; }
  idx -= 16384;
  if (idx < 65536) {
    int rowp = (int)(idx >> 6), f = (int)(idx & 63);
    int r = rowp_to_orig(rowp);
    float a = 0.f;
    for (int k = 0; k < 256; ++k) a += w_ih[r * 256 + k] * enc_w[k * 64 + f];
    CW[idx] = f2bf(a);
    return;
  }
  idx -= 65536;
  if (idx < 1024) {
    int r = rowp_to_orig((int)idx);
    float a = b_ih[r] + b_hh[r];
    for (int k = 0; k < 256; ++k) a += w_ih[r * 256 + k] * enc_b[k];
    CB[idx] = a;
    return;
  }
  idx -= 1024;
  if (idx < 1024) {
    int r = rowp_to_orig((int)idx);
    B1P[idx] = b_ih[1024 + r] + b_hh[1024 + r];
    return;
  }
  idx -= 1024;
  if (idx < 524288) {   // WHHP: flat = ((((l*4+p)*4+w)*4+t)*8+kc)*512 + lane*8 + e
    int l = (int)(idx >> 18);
    int rem = (int)(idx & 262143);
    int e = rem & 7, lane = (rem >> 3) & 63, kc = (rem >> 9) & 7;
    int t = (rem >> 12) & 3, wv = (rem >> 14) & 3, pp = (rem >> 16) & 3;
    int u = lane & 15, qd = lane >> 4;
    int g = u & 3;
    int j = wv * 16 + ((u >> 2) << 2) + t;
    int r = g * 256 + pp * 64 + j;
    int k = kc * 32 + qd * 8 + e;
    WHHP[idx] = f2bf(w_hh[(size_t)l * 262144 + (size_t)r * 256 + k]);
    return;
  }
  idx -= 524288;
  if (idx < 262144) {   // WIH1P (l=1)
    int rem = (int)idx;
    int e = rem & 7, lane = (rem >> 3) & 63, kc = (rem >> 9) & 7;
    int t = (rem >> 12) & 3, wv = (rem >> 14) & 3, pp = (rem >> 16) & 3;
    int u = lane & 15, qd = lane >> 4;
    int g = u & 3;
    int j = wv * 16 + ((u >> 2) << 2) + t;
    int r = g * 256 + pp * 64 + j;
    int k = kc * 32 + qd * 8 + e;
    WIH1P[idx] = f2bf(w_ih[262144 + (size_t)r * 256 + k]);
    return;
  }
  idx -= 262144;
  if (idx < 1024) ZERO[idx] = 0;
}

// ---------------- generic bf16 GEMM:  C(MxN) = A(MxK) * B(NxK)^T + bias ----------------
template<int KTILES, int OUTBF, int BMODE, int AF32>
__global__ __launch_bounds__(256, 1) void gemm_bt(
    const void* __restrict__ Av, const u16* __restrict__ B, void* __restrict__ Cv,
    const float* __restrict__ bias, size_t ldc)
{
  constexpr int K = KTILES * 64;
  __shared__ __align__(16) u16 Asl[64 * 72];
  __shared__ __align__(16) u16 Bsl[64 * 72];
  const int tid = threadIdx.x;
  const int w = tid >> 6, lane = tid & 63, lm = lane & 15, quad = lane >> 4;
  const size_t m0 = (size_t)blockIdx.y * 64, n0 = (size_t)blockIdx.x * 64;

  f32x4 acc[4];
#pragma unroll
  for (int nt = 0; nt < 4; ++nt) { f32x4 z = {0.f, 0.f, 0.f, 0.f}; acc[nt] = z; }

  for (int kb = 0; kb < KTILES; ++kb) {
    if (AF32) {
      const float* Af = (const float*)Av;
#pragma unroll
      for (int c = 0; c < 4; ++c) {
        int idx = c * 256 + tid;
        int row = idx >> 4, k4 = idx & 15;
        float4 v = *(const float4*)(Af + (m0 + row) * (size_t)K + kb * 64 + k4 * 4);
        u64 pv = (u64)f2bf(v.x) | ((u64)f2bf(v.y) << 16) |
                 ((u64)f2bf(v.z) << 32) | ((u64)f2bf(v.w) << 48);
        *(u64*)(&Asl[row * 72 + k4 * 4]) = pv;
      }
    } else {
      const u16* Ab = (const u16*)Av;
#pragma unroll
      for (int c = 0; c < 2; ++c) {
        int idx = c * 256 + tid;
        int row = idx >> 3, k8 = idx & 7;
        *(uint4*)(&Asl[row * 72 + k8 * 8]) =
            *(const uint4*)(Ab + (m0 + row) * (size_t)K + kb * 64 + k8 * 8);
      }
    }
#pragma unroll
    for (int c = 0; c < 2; ++c) {
      int idx = c * 256 + tid;
      int row = idx >> 3, k8 = idx & 7;
      *(uint4*)(&Bsl[row * 72 + k8 * 8]) =
          *(const uint4*)(B + (n0 + row) * (size_t)K + kb * 64 + k8 * 8);
    }
    __syncthreads();
#pragma unroll
    for (int kc = 0; kc < 2; ++kc) {
      short8 a = *(const short8*)(&Asl[(w * 16 + lm) * 72 + kc * 32 + quad * 8]);
#pragma unroll
      for (int nt = 0; nt < 4; ++nt) {
        short8 b = *(const short8*)(&Bsl[(nt * 16 + lm) * 72 + kc * 32 + quad * 8]);
        acc[nt] = __builtin_amdgcn_mfma_f32_16x16x32_bf16(a, b, acc[nt], 0, 0, 0);
      }
    }
    __syncthreads();
  }
#pragma unroll
  for (int nt = 0; nt < 4; ++nt) {
    size_t n = n0 + nt * 16 + lm;
    float bn = (BMODE == 1) ? bias[n] : 0.f;
#pragma unroll
    for (int r = 0; r < 4; ++r) {
      size_t m = m0 + w * 16 + quad * 4 + r;
      float v = acc[nt][r] + ((BMODE == 2) ? bias[m] : bn);
      if (OUTBF) ((u16*)Cv)[m * ldc + n] = f2bf(v);
      else       ((float*)Cv)[m * ldc + n] = v;
    }
  }
}

// ---------------- fused 2-layer pipelined recurrence (16 wgs, agent scope) ----------------
// role = blockIdx.x: layer = role>>3, p = role&3, n2 = (role>>2)&1.
// flags[i*64]: 0..7 layer0 (n2*4+p), 8..15 layer1. hx rings: [4][64 b][256 j].
__global__ __launch_bounds__(256, 1) void lstm_fused(
    const u16* __restrict__ xg0, u16* __restrict__ x2,
    const u16* __restrict__ whhp, const u16* __restrict__ wih1p,
    const float* __restrict__ b1p,
    u16* __restrict__ hx0, u16* __restrict__ hx1,
    int* __restrict__ flags, float* __restrict__ cstb, int base)
{
  __shared__ __align__(16) u16 Hl[2][32 * 264];   // +8 u16 row pad
  const int tid = threadIdx.x;
  const int role = blockIdx.x;
  const int layer = role >> 3, p = role & 3, n2 = (role >> 2) & 1;
  const int lane = tid & 63, w = tid >> 6, lm = lane & 15, quad = lane >> 4;

  // ---- weights into VGPR fragments ----
  short8 wfh[4][8], wfi[4][8];
  {
    const u16* wp = whhp + (size_t)((layer * 4 + p) * 4 + w) * 16384 + lane * 8;
#pragma unroll
    for (int t = 0; t < 4; ++t)
#pragma unroll
      for (int kc = 0; kc < 8; ++kc)
        wfh[t][kc] = *(const short8*)(wp + (t * 8 + kc) * 512);
  }
  f32x4 bias_f[4];
  if (layer) {
    const u16* wp = wih1p + (size_t)(p * 4 + w) * 16384 + lane * 8;
#pragma unroll
    for (int t = 0; t < 4; ++t)
#pragma unroll
      for (int kc = 0; kc < 8; ++kc)
        wfi[t][kc] = *(const short8*)(wp + (t * 8 + kc) * 512);
#pragma unroll
    for (int t = 0; t < 4; ++t)
      bias_f[t] = *(const f32x4*)(b1p + p * 256 + (w * 4 + t) * 16 + quad * 4);
  }

  float* cp = cstb + (size_t)(((layer * 4 + p) * 2 + n2) * 256 + tid) * 8;
  float cst[4][2];
  if (base) {
#pragma unroll
    for (int t = 0; t < 4; ++t) { cst[t][0] = cp[t * 2]; cst[t][1] = cp[t * 2 + 1]; }
  } else {
#pragma unroll
    for (int t = 0; t < 4; ++t) { cst[t][0] = 0.f; cst[t][1] = 0.f; }
  }

  int* myflag = flags + (layer * 8 + n2 * 4 + p) * 64;
  const int jcol = p * 64 + w * 16 + quad * 4;
  u16* myhx = layer ? hx1 : hx0;

  // poll setup: threads 0..3 watch layer-0 group (same half), 4..7 layer-1 group.
  // lastv = register-cached monotone flag value => poll MALL only when stale.
  int* pollp = nullptr;
  int lastv = base;
  if (tid < 8) {
    int fi = (tid < 4) ? (n2 * 4 + tid) : (8 + n2 * 4 + (tid - 4));
    pollp = flags + fi * 64;
  }

  for (int s = 1; s <= CS; ++s) {
    const int sA = base + s;
    // xg0 loads early (layer 0) to overlap with the poll
    u64 xv[4][2];
    if (layer == 0) {
#pragma unroll
      for (int t = 0; t < 4; ++t)
#pragma unroll
        for (int nt = 0; nt < 2; ++nt)
          xv[t][nt] = *(const u64*)(xg0 +
              ((size_t)(s - 1) * 64 + n2 * 32 + nt * 16 + lm) * 1024 +
              p * 256 + (w * 4 + t) * 16 + quad * 4);
    }
    // ---- cached flag polls ----
    const int needA = layer ? sA : sA - 1;        // layer-0 group requirement
    const int needB = layer ? sA - 1 : sA - 4;    // layer-1 group requirement
    if (tid < 8) {
      const int need = (tid < 4) ? needA : needB;
      if (lastv < need) {
        int v;
        do {
          v = __hip_atomic_load(pollp, __ATOMIC_RELAXED, __HIP_MEMORY_SCOPE_AGENT);
        } while (v < need);
        lastv = v;
      }
    }
    __syncthreads();
    // ---- coalesced gather -> LDS (agent-scope u64 atomic loads) ----
    if (layer == 0) {
      if (sA >= 2) {
        const u16* src = hx0 + (size_t)((sA - 1) & 3) * 16384;
#pragma unroll
        for (int i = 0; i < 8; ++i) {
          int fi = i * 256 + tid, lb = fi >> 6, j4 = fi & 63;
          u64 v = __hip_atomic_load(
              (const u64*)(src + ((size_t)(n2 * 32 + lb) * 256 + j4 * 4)),
              __ATOMIC_RELAXED, __HIP_MEMORY_SCOPE_AGENT);
          *(u64*)(&Hl[0][lb * 264 + j4 * 4]) = v;
        }
      }
    } else {
      const u16* s0 = hx0 + (size_t)(sA & 3) * 16384;
#pragma unroll
      for (int i = 0; i < 8; ++i) {
        int fi = i * 256 + tid, lb = fi >> 6, j4 = fi & 63;
        u64 v = __hip_atomic_load(
            (const u64*)(s0 + ((size_t)(n2 * 32 + lb) * 256 + j4 * 4)),
            __ATOMIC_RELAXED, __HIP_MEMORY_SCOPE_AGENT);
        *(u64*)(&Hl[0][lb * 264 + j4 * 4]) = v;
      }
      if (sA >= 2) {
        const u16* s1 = hx1 + (size_t)((sA - 1) & 3) * 16384;
#pragma unroll
        for (int i = 0; i < 8; ++i) {
          int fi = i * 256 + tid, lb = fi >> 6, j4 = fi & 63;
          u64 v = __hip_atomic_load(
              (const u64*)(s1 + ((size_t)(n2 * 32 + lb) * 256 + j4 * 4)),
              __ATOMIC_RELAXED, __HIP_MEMORY_SCOPE_AGENT);
          *(u64*)(&Hl[1][lb * 264 + j4 * 4]) = v;
        }
      }
    }
    __syncthreads();
    // ---- acc init ----
    f32x4 acc[4][2];
    if (layer == 0) {
#pragma unroll
      for (int t = 0; t < 4; ++t)
#pragma unroll
        for (int nt = 0; nt < 2; ++nt) {
          u64 v = xv[t][nt];
          f32x4 tt = { bf2f((u16)v), bf2f((u16)(v >> 16)),
                       bf2f((u16)(v >> 32)), bf2f((u16)(v >> 48)) };
          acc[t][nt] = tt;
        }
    } else {
#pragma unroll
      for (int t = 0; t < 4; ++t)
#pragma unroll
        for (int nt = 0; nt < 2; ++nt) acc[t][nt] = bias_f[t];
    }
    // ---- MFMA chains ----
    if (layer == 0) {
      if (sA >= 2) {
#pragma unroll
        for (int kc = 0; kc < 8; ++kc) {
          short8 b0[2];
#pragma unroll
          for (int nt = 0; nt < 2; ++nt)
            b0[nt] = *(const short8*)(&Hl[0][(nt * 16 + lm) * 264 + kc * 32 + quad * 8]);
#pragma unroll
          for (int t = 0; t < 4; ++t)
#pragma unroll
            for (int nt = 0; nt < 2; ++nt)
              acc[t][nt] = __builtin_amdgcn_mfma_f32_16x16x32_bf16(
                  wfh[t][kc], b0[nt], acc[t][nt], 0, 0, 0);
        }
      }
    } else {
#pragma unroll
      for (int kc = 0; kc < 8; ++kc) {
        short8 b0[2];
#pragma unroll
        for (int nt = 0; nt < 2; ++nt)
          b0[nt] = *(const short8*)(&Hl[0][(nt * 16 + lm) * 264 + kc * 32 + quad * 8]);
#pragma unroll
        for (int t = 0; t < 4; ++t)
#pragma unroll
          for (int nt = 0; nt < 2; ++nt)
            acc[t][nt] = __builtin_amdgcn_mfma_f32_16x16x32_bf16(
                wfi[t][kc], b0[nt], acc[t][nt], 0, 0, 0);
      }
      if (sA >= 2) {
#pragma unroll
        for (int kc = 0; kc < 8; ++kc) {
          short8 b1[2];
#pragma unroll
          for (int nt = 0; nt < 2; ++nt)
            b1[nt] = *(const short8*)(&Hl[1][(nt * 16 + lm) * 264 + kc * 32 + quad * 8]);
#pragma unroll
          for (int t = 0; t < 4; ++t)
#pragma unroll
            for (int nt = 0; nt < 2; ++nt)
              acc[t][nt] = __builtin_amdgcn_mfma_f32_16x16x32_bf16(
                  wfh[t][kc], b1[nt], acc[t][nt], 0, 0, 0);
        }
      }
    }
    // ---- nonlinearity + immediate hx publish (per nt), then barrier+flag ----
    u16* hd = myhx + (size_t)(sA & 3) * 16384;
    u64 hv[2];
#pragma unroll
    for (int nt = 0; nt < 2; ++nt) {
      u64 h = 0;
#pragma unroll
      for (int t = 0; t < 4; ++t) {
        float iv = sigf(acc[t][nt][0]);
        float fv = sigf(acc[t][nt][1]);
        float gv = tanhf_fast(acc[t][nt][2]);
        float ov = sigf(acc[t][nt][3]);
        float cv = fv * cst[t][nt] + iv * gv;
        cst[t][nt] = cv;
        h |= (u64)f2bf(ov * tanhf_fast(cv)) << (16 * t);
      }
      hv[nt] = h;
      int b = n2 * 32 + nt * 16 + lm;
      __hip_atomic_store((u64*)(hd + (size_t)b * 256 + jcol), h,
                         __ATOMIC_RELAXED, __HIP_MEMORY_SCOPE_AGENT);
    }
    __syncthreads();   // vmcnt(0) drain: hx data globally visible before flag
    if (tid == 0)
      __hip_atomic_store(myflag, sA, __ATOMIC_RELAXED, __HIP_MEMORY_SCOPE_AGENT);
    // x2 store AFTER the flag — off the critical path (stream order covers decoder)
    if (layer) {
#pragma unroll
      for (int nt = 0; nt < 2; ++nt) {
        int b = n2 * 32 + nt * 16 + lm;
        *(u64*)(x2 + ((size_t)(s - 1) * 64 + b) * 256 + jcol) = hv[nt];
      }
    }
  }
#pragma unroll
  for (int t = 0; t < 4; ++t) { cp[t * 2] = cst[t][0]; cp[t * 2 + 1] = cst[t][1]; }
}

// ---------------- launch ----------------
extern "C" void kernel_launch(void* const* d_in, const int* in_sizes, int n_in,
                              void* d_out, int out_size, void* d_ws, size_t ws_size,
                              hipStream_t stream)
{
  const float* in0   = (const float*)d_in[0];
  const float* enc_w = (const float*)d_in[1];
  const float* enc_b = (const float*)d_in[2];
  const float* w_ih  = (const float*)d_in[3];
  const float* w_hh  = (const float*)d_in[4];
  const float* b_ih  = (const float*)d_in[5];
  const float* b_hh  = (const float*)d_in[6];
  const float* dec_w = (const float*)d_in[7];
  const float* dec_b = (const float*)d_in[8];

  char* ws = (char*)d_ws;
  u16*   XG    = (u16*)(ws);                 // 33,554,432  xg0 chunk [CN][1024]
  u16*   X2    = (u16*)(ws + 33554432);      //  8,388,608  x2 chunk [CN][256]
  u16*   WHHP  = (u16*)(ws + 41943040);      //  1,048,576
  u16*   WIH1P = (u16*)(ws + 42991616);      //    524,288
  u16*   CW    = (u16*)(ws + 43515904);      //    131,072
  u16*   WDEC  = (u16*)(ws + 43646976);      //     32,768
  float* CB    = (float*)(ws + 43679744);    //      4,096
  float* B1P   = (float*)(ws + 43683840);    //      4,096
  u16*   HX0   = (u16*)(ws + 43687936);      //    131,072  ring 4 x 32KB
  u16*   HX1   = (u16*)(ws + 43819008);      //    131,072
  float* CST   = (float*)(ws + 43950080);    //    131,072
  int*   FLAGS = (int*)(ws + 44081152);      //      4,096  16 flags x 256B

  if (ws_size < 44085248) return;   // diagnostic guard

  prep_kernel<<<dim3((PREP_TOTAL + 255) / 256), 256, 0, stream>>>(
      enc_w, enc_b, w_ih, w_hh, b_ih, b_hh, dec_w,
      WDEC, CW, CB, B1P, WHHP, WIH1P, FLAGS);

  for (int c = 0; c < NCH; ++c) {
    const float* inc = in0 + (size_t)c * CN * 64;
    float* outc = (float*)d_out + (size_t)c * CN * 64;
    // xg0 = inc @ CW^T + CB  (encoder folded in; M=CN, N=1024, K=64)
    gemm_bt<1, 1, 1, 1><<<dim3(16, CN / 64), 256, 0, stream>>>(inc, CW, XG, CB, 1024);
    // fused pipelined 2-layer recurrence
    lstm_fused<<<dim3(16), 256, 0, stream>>>(XG, X2, WHHP, WIH1P, B1P,
                                             HX0, HX1, FLAGS, CST, c * CS);
    // decoder: outc = x2 @ dec_w^T + dec_b  (M=CN, N=64, K=256), fp32 out
    gemm_bt<4, 0, 1, 0><<<dim3(1, CN / 64), 256, 0, stream>>>(X2, WDEC, (void*)outc, dec_b, 64);
  }

  (void)in_sizes; (void)n_in; (void)out_size;
}